// Round 4
// baseline (355.625 us; speedup 1.0000x reference)
//
#include <hip/hip_runtime.h>
#include <hip/hip_bf16.h>
#include <math.h>

#define NN   50000
#define EE   800000
#define INF  512
#define HIDF 256
#define OUTF 64
#define MTILES (NN/16)   // 3125

using short8 = __attribute__((ext_vector_type(8))) short;
using short4v = __attribute__((ext_vector_type(4))) short;
using f32x4  = __attribute__((ext_vector_type(4))) float;

static __device__ __forceinline__ short f2bf(float f){
  unsigned u = __builtin_bit_cast(unsigned, f);
  u += 0x7fff + ((u >> 16) & 1);        // round-to-nearest-even
  return (short)(u >> 16);
}
static __device__ __forceinline__ float bf2f(short s){
  unsigned u = ((unsigned)(unsigned short)s) << 16;
  return __builtin_bit_cast(float, u);
}

// ---- fused prep: row_ptr (blocks 0..195) | W1 pack (196..707) | W2^T (708..771) ----
__global__ void k_prep(const int* __restrict__ a_row, int* __restrict__ row_ptr,
                       const float* __restrict__ W1, short* __restrict__ W1p,
                       const float* __restrict__ W2, short* __restrict__ W2bT){
  int b = blockIdx.x, tid = threadIdx.x;
  if (b < 196){
    int i = b * 256 + tid;
    if (i > NN) return;
    int lo = 0, hi = EE;
    while (lo < hi){ int mid = (lo + hi) >> 1; if (a_row[mid] < i) lo = mid + 1; else hi = mid; }
    row_ptr[i] = lo;
  } else if (b < 708){
    int idx = (b - 196) * 256 + tid;        // 512*256 elements
    int k = idx >> 8, col = idx & 255;
    int kk = k >> 5, k2 = k & 31;
    W1p[((kk << 8) + col) * 32 + k2] = f2bf(W1[idx]);
  } else {
    int idx = (b - 708) * 256 + tid;        // 256*64 elements
    int k = idx >> 6, n = idx & 63;
    W2bT[n * HIDF + k] = f2bf(W2[idx]);
  }
}

// ---------------- GEMM1: XW1b[NN,HIDF](bf16) = X[NN,INF] @ W1 ----------------
// barrier-free: wave = 32 rows x 256 cols, B-frags straight from global
// (W1p = 256 KB, L1/L2-resident; each B read is a fully-coalesced 1KB load).
// grid = 782 blocks x 2 waves -> 1563 waves, no __syncthreads anywhere.
__global__ __launch_bounds__(128) void k_gemm1(const float* __restrict__ X,
                                               const short* __restrict__ W1p,
                                               short* __restrict__ XW1b){
  int wave = threadIdx.x >> 6, lane = threadIdx.x & 63;
  int l16 = lane & 15, quad = lane >> 4;
  int m0 = blockIdx.x * 64 + wave * 32;
  int r0 = min(m0 + l16, NN - 1);             // clamp reads; stores are guarded
  int r1 = min(m0 + 16 + l16, NN - 1);
  const float* arow0 = X + (size_t)r0 * INF + quad * 8;
  const float* arow1 = X + (size_t)r1 * INF + quad * 8;

  f32x4 acc0[16], acc1[16];
  #pragma unroll
  for (int t = 0; t < 16; t++){ acc0[t] = (f32x4){0.f,0.f,0.f,0.f}; acc1[t] = (f32x4){0.f,0.f,0.f,0.f}; }

  for (int kk = 0; kk < INF/32; kk++){
    const float4* ap0 = (const float4*)(arow0 + kk * 32);
    const float4* ap1 = (const float4*)(arow1 + kk * 32);
    float4 a00 = ap0[0], a01 = ap0[1];
    float4 a10 = ap1[0], a11 = ap1[1];
    short8 af0, af1;
    af0[0]=f2bf(a00.x); af0[1]=f2bf(a00.y); af0[2]=f2bf(a00.z); af0[3]=f2bf(a00.w);
    af0[4]=f2bf(a01.x); af0[5]=f2bf(a01.y); af0[6]=f2bf(a01.z); af0[7]=f2bf(a01.w);
    af1[0]=f2bf(a10.x); af1[1]=f2bf(a10.y); af1[2]=f2bf(a10.z); af1[3]=f2bf(a10.w);
    af1[4]=f2bf(a11.x); af1[5]=f2bf(a11.y); af1[6]=f2bf(a11.z); af1[7]=f2bf(a11.w);

    const short* bchunk = W1p + kk * (256*32);
    #pragma unroll
    for (int nt = 0; nt < 16; nt++){
      short8 bf = *(const short8*)(bchunk + (nt*16 + l16) * 32 + quad * 8);
      acc0[nt] = __builtin_amdgcn_mfma_f32_16x16x32_bf16(af0, bf, acc0[nt], 0, 0, 0);
      acc1[nt] = __builtin_amdgcn_mfma_f32_16x16x32_bf16(af1, bf, acc1[nt], 0, 0, 0);
    }
  }
  #pragma unroll
  for (int nt = 0; nt < 16; nt++){
    int col = nt*16 + l16;
    #pragma unroll
    for (int r = 0; r < 4; r++){
      int row0 = m0 + quad*4 + r;
      int row1 = m0 + 16 + quad*4 + r;
      if (row0 < NN) XW1b[(size_t)row0 * HIDF + col] = f2bf(acc0[nt][r]);
      if (row1 < NN) XW1b[(size_t)row1 * HIDF + col] = f2bf(acc1[nt][r]);
    }
  }
}

// ---- SpMM1 + ReLU + dropout: one wave/row, 8 edge-groups x 8 lanes x 64B,
// ---- unroll x2 -> 8 independent 16B gathers in flight per lane ----
__global__ __launch_bounds__(256) void k_spmm1(const int* __restrict__ row_ptr,
                                               const int* __restrict__ a_col,
                                               const float* __restrict__ a_val,
                                               const short* __restrict__ XW1b,
                                               const int* __restrict__ drop_mask,
                                               short* __restrict__ hb){
  int wave = threadIdx.x >> 6, lane = threadIdx.x & 63;
  int r = blockIdx.x * 4 + wave;
  int s = row_ptr[r], e = row_ptr[r+1];
  int g = lane >> 3;          // edge subgroup: 8 edges in flight
  int c8 = lane & 7;          // this lane covers cols c8*32 .. +31
  float acc[32];
  #pragma unroll
  for (int j = 0; j < 32; j++) acc[j] = 0.f;

  int i = s + g;
  for (; i + 8 < e; i += 16){
    float v0 = a_val[i];     int c0 = a_col[i];
    float v1 = a_val[i+8];   int c1 = a_col[i+8];
    const short* p0 = XW1b + (size_t)c0 * HIDF + c8 * 32;
    const short* p1 = XW1b + (size_t)c1 * HIDF + c8 * 32;
    short8 x0[4], x1[4];
    #pragma unroll
    for (int q = 0; q < 4; q++){ x0[q] = *(const short8*)(p0 + q*8); }
    #pragma unroll
    for (int q = 0; q < 4; q++){ x1[q] = *(const short8*)(p1 + q*8); }
    #pragma unroll
    for (int q = 0; q < 4; q++)
      #pragma unroll
      for (int j = 0; j < 8; j++){
        acc[q*8+j] += v0 * bf2f(x0[q][j]);
        acc[q*8+j] += v1 * bf2f(x1[q][j]);
      }
  }
  for (; i < e; i += 8){
    float v = a_val[i];  int c = a_col[i];
    const short* p = XW1b + (size_t)c * HIDF + c8 * 32;
    #pragma unroll
    for (int q = 0; q < 4; q++){
      short8 x = *(const short8*)(p + q*8);
      #pragma unroll
      for (int j = 0; j < 8; j++) acc[q*8+j] += v * bf2f(x[j]);
    }
  }
  #pragma unroll
  for (int j = 0; j < 32; j++){
    acc[j] += __shfl_xor(acc[j], 8);
    acc[j] += __shfl_xor(acc[j], 16);
    acc[j] += __shfl_xor(acc[j], 32);
  }
  if (lane < 8){
    const int* dm = drop_mask + (size_t)r * HIDF + c8 * 32;
    short* hp = hb + (size_t)r * HIDF + c8 * 32;
    #pragma unroll
    for (int q = 0; q < 4; q++){
      short8 o;
      #pragma unroll
      for (int j = 0; j < 8; j++)
        o[j] = f2bf(fmaxf(acc[q*8+j], 0.f) * (float)dm[q*8+j] * 2.0f);
      *(short8*)(hp + q*8) = o;
    }
  }
}

// ---------------- GEMM2: HW2b[NN,OUTF](bf16) = h[NN,HIDF] @ W2 ----------------
__global__ __launch_bounds__(256) void k_gemm2(const short* __restrict__ A,  // hb
                                               const short* __restrict__ BT, // [OUTF][HIDF]
                                               short* __restrict__ C){
  int wave = threadIdx.x >> 6, lane = threadIdx.x & 63;
  int tile_m = blockIdx.x * 4 + wave;
  if (tile_m >= MTILES) return;
  int m0 = tile_m * 16, l16 = lane & 15, quad = lane >> 4;

  f32x4 acc[4];
  #pragma unroll
  for (int t = 0; t < 4; t++) acc[t] = (f32x4){0.f,0.f,0.f,0.f};

  const short* ar = A + (size_t)(m0 + l16) * HIDF + quad * 8;
  for (int kk = 0; kk < HIDF/32; kk++){
    short8 af = *(const short8*)(ar + kk * 32);
    #pragma unroll
    for (int nt = 0; nt < 4; nt++){
      short8 bf = *(const short8*)(BT + (size_t)(nt*16 + l16) * HIDF + kk*32 + quad*8);
      acc[nt] = __builtin_amdgcn_mfma_f32_16x16x32_bf16(af, bf, acc[nt], 0, 0, 0);
    }
  }
  #pragma unroll
  for (int nt = 0; nt < 4; nt++){
    int col = nt*16 + l16;
    #pragma unroll
    for (int r = 0; r < 4; r++)
      C[(size_t)(m0 + quad*4 + r) * OUTF + col] = f2bf(acc[nt][r]);
  }
}

// -- SpMM2 + log_softmax: one wave/row, 8 edge-groups x 8 lanes x 16B, unroll x2 --
__global__ __launch_bounds__(256) void k_spmm2_lsm(const int* __restrict__ row_ptr,
                                                   const int* __restrict__ a_col,
                                                   const float* __restrict__ a_val,
                                                   const short* __restrict__ HW2b,
                                                   float* __restrict__ out){
  int wave = threadIdx.x >> 6, lane = threadIdx.x & 63;
  int r = blockIdx.x * 4 + wave;
  int s = row_ptr[r], e = row_ptr[r+1];
  int g = lane >> 3;          // edge subgroup (8 edges in flight, x2 unroll = 16)
  int c8 = lane & 7;          // this lane covers classes c8*8 .. +7
  float acc[8];
  #pragma unroll
  for (int j = 0; j < 8; j++) acc[j] = 0.f;

  int i = s + g;
  for (; i + 8 < e; i += 16){
    float v0 = a_val[i];    int c0 = a_col[i];
    float v1 = a_val[i+8];  int c1 = a_col[i+8];
    short8 x0 = *(const short8*)(HW2b + (size_t)c0 * OUTF + c8 * 8);
    short8 x1 = *(const short8*)(HW2b + (size_t)c1 * OUTF + c8 * 8);
    #pragma unroll
    for (int j = 0; j < 8; j++){ acc[j] += v0 * bf2f(x0[j]); acc[j] += v1 * bf2f(x1[j]); }
  }
  for (; i < e; i += 8){
    float v = a_val[i];  int c = a_col[i];
    short8 x = *(const short8*)(HW2b + (size_t)c * OUTF + c8 * 8);
    #pragma unroll
    for (int j = 0; j < 8; j++) acc[j] += v * bf2f(x[j]);
  }
  #pragma unroll
  for (int j = 0; j < 8; j++){
    acc[j] += __shfl_xor(acc[j], 8);
    acc[j] += __shfl_xor(acc[j], 16);
    acc[j] += __shfl_xor(acc[j], 32);
  }
  // log_softmax across 64 classes (classes split over c8 = lane&7)
  float m = acc[0];
  #pragma unroll
  for (int j = 1; j < 8; j++) m = fmaxf(m, acc[j]);
  #pragma unroll
  for (int o = 1; o <= 4; o <<= 1) m = fmaxf(m, __shfl_xor(m, o));
  float ssum = 0.f;
  #pragma unroll
  for (int j = 0; j < 8; j++) ssum += expf(acc[j] - m);
  #pragma unroll
  for (int o = 1; o <= 4; o <<= 1) ssum += __shfl_xor(ssum, o);
  float ls = logf(ssum);
  if (lane < 8){
    float4 o0 = { acc[0]-m-ls, acc[1]-m-ls, acc[2]-m-ls, acc[3]-m-ls };
    float4 o1 = { acc[4]-m-ls, acc[5]-m-ls, acc[6]-m-ls, acc[7]-m-ls };
    float* op = out + (size_t)r * OUTF + c8 * 8;
    *(float4*)(op)     = o0;
    *(float4*)(op + 4) = o1;
  }
}

extern "C" void kernel_launch(void* const* d_in, const int* in_sizes, int n_in,
                              void* d_out, int out_size, void* d_ws, size_t ws_size,
                              hipStream_t stream) {
  const float* X      = (const float*)d_in[0];
  const float* W1     = (const float*)d_in[1];
  const float* W2     = (const float*)d_in[2];
  const int*   a_row  = (const int*)d_in[3];
  const int*   a_col  = (const int*)d_in[4];
  const float* a_val  = (const float*)d_in[5];
  const int*   drop   = (const int*)d_in[6];
  float*       out    = (float*)d_out;

  char* ws = (char*)d_ws;
  int*   row_ptr = (int*)  (ws);                       //   200,704 B
  short* W1p     = (short*)(ws + 200704);              //   262,144 B
  short* W2bT    = (short*)(ws + 462848);              //    32,768 B
  short* XW1b    = (short*)(ws + 495616);              // 25,600,000 B
  short* hb      = (short*)(ws + 26095616);            // 25,600,000 B
  short* HW2b    = (short*)(ws + 51695616);            //  6,400,000 B (end ~58.1 MB)

  k_prep<<<772, 256, 0, stream>>>(a_row, row_ptr, W1, W1p, W2, W2bT);
  k_gemm1<<<(NN + 63)/64, 128, 0, stream>>>(X, W1p, XW1b);
  k_spmm1<<<NN/4, 256, 0, stream>>>(row_ptr, a_col, a_val, XW1b, drop, hb);
  k_gemm2<<<(MTILES + 3)/4, 256, 0, stream>>>(hb, W2bT, HW2b);
  k_spmm2_lsm<<<NN/4, 256, 0, stream>>>(row_ptr, a_col, a_val, HW2b, out);
}